// Round 1
// baseline (9642.594 us; speedup 1.0000x reference)
//
#include <hip/hip_runtime.h>
#include <hip/hip_bf16.h>

// LSTM: B=32, T=512, D=512, H=1024, gates 4H=4096, gate order i,f,g,o.
// Strategy: fused z_t = [h|x_t] @ [Wh;Wx] + b with K=1536, split-bf16 (hi/lo)
// 3-MFMA emulation for ~fp32 accuracy. One kernel launch per timestep.

#define B_   32
#define T_   512
#define D_   512
#define H_   1024
#define KTOT 1536
#define N4H  4096

typedef __bf16 bf16_t;
typedef __bf16 bf16x8 __attribute__((ext_vector_type(8)));
typedef __bf16 bf16x4 __attribute__((ext_vector_type(4)));
typedef float f32x4 __attribute__((ext_vector_type(4)));

// ---------------------------------------------------------------------------
// Weight transpose + hi/lo bf16 split.
// Combined W rows k in [0,1536): k<1024 -> Wh[k][n], else Wx[k-1024][n].
// Output Wt[n][k] (k contiguous) so MFMA B-fragments are 16B contiguous loads.
__global__ void wconv_kernel(const float* __restrict__ Wx,
                             const float* __restrict__ Wh,
                             bf16_t* __restrict__ WtHi,
                             bf16_t* __restrict__ WtLo) {
    __shared__ float tile[32][33];
    int k0 = blockIdx.x * 32;   // 48 tiles over K=1536 (1024 boundary aligned)
    int n0 = blockIdx.y * 32;   // 128 tiles over N=4096
    int tx = threadIdx.x;       // 0..31
    int ty = threadIdx.y;       // 0..7
    for (int i = ty; i < 32; i += 8) {
        int k = k0 + i;
        float v = (k < H_) ? Wh[(size_t)k * N4H + n0 + tx]
                           : Wx[(size_t)(k - H_) * N4H + n0 + tx];
        tile[i][tx] = v;
    }
    __syncthreads();
    for (int i = ty; i < 32; i += 8) {
        int n = n0 + i;
        float v = tile[tx][i];
        bf16_t hi = (bf16_t)v;
        float r = v - (float)hi;
        WtHi[(size_t)n * KTOT + k0 + tx] = hi;
        WtLo[(size_t)n * KTOT + k0 + tx] = (bf16_t)r;
    }
}

// ---------------------------------------------------------------------------
// Input hi/lo bf16 split (elementwise, float4-vectorized). Exactly covers
// B*T*D/4 = 2097152 groups with grid 8192 x 256.
__global__ void xconv_kernel(const float4* __restrict__ X,
                             bf16_t* __restrict__ XHi,
                             bf16_t* __restrict__ XLo) {
    int i = blockIdx.x * blockDim.x + threadIdx.x;
    float4 v = X[i];
    float arr[4] = {v.x, v.y, v.z, v.w};
    bf16x4 hi, lo;
#pragma unroll
    for (int j = 0; j < 4; ++j) {
        bf16_t h = (bf16_t)arr[j];
        hi[j] = h;
        lo[j] = (bf16_t)(arr[j] - (float)h);
    }
    *(bf16x4*)(XHi + 4 * (size_t)i) = hi;
    *(bf16x4*)(XLo + 4 * (size_t)i) = lo;
}

// ---------------------------------------------------------------------------
// One LSTM timestep. Grid: 64 blocks (16 h-columns each), 256 threads (4
// waves; wave w computes gate w for this block's 16 columns, M=32 batches as
// two 16x16 MFMA M-tiles). A = [h | x_t] staged hi/lo in LDS, shared by all
// 4 waves. B (Wt) read directly from global (L2-resident, 25 MB working set).
__global__ __launch_bounds__(256) void step_kernel(
    const bf16_t* __restrict__ WtHi, const bf16_t* __restrict__ WtLo,
    const bf16_t* __restrict__ XHi,  const bf16_t* __restrict__ XLo,
    const bf16_t* __restrict__ hInHi, const bf16_t* __restrict__ hInLo,
    bf16_t* __restrict__ hOutHi, bf16_t* __restrict__ hOutLo,
    float* __restrict__ c,
    const float* __restrict__ bias,
    const int* __restrict__ seqlen,
    float* __restrict__ out,
    int t) {
    __shared__ bf16_t aHi[32][264];   // 256-wide K-chunk of A, +8 pad
    __shared__ bf16_t aLo[32][264];
    __shared__ float zsm[4][32][16];  // gate exchange: [gate][batch][col]

    int tid  = threadIdx.x;
    int wave = tid >> 6;
    int lane = tid & 63;
    int quad = lane >> 4;
    int lcol = lane & 15;            // MFMA col (B n-index) and A row m
    int hc0  = blockIdx.x * 16;

    int nz = wave * H_ + hc0 + lcol; // gate column in z / row of Wt
    const bf16_t* wHiRow = WtHi + (size_t)nz * KTOT;
    const bf16_t* wLoRow = WtLo + (size_t)nz * KTOT;

    f32x4 acc0 = {0.f, 0.f, 0.f, 0.f};  // batches 0..15
    f32x4 acc1 = {0.f, 0.f, 0.f, 0.f};  // batches 16..31

    for (int chunk = 0; chunk < 6; ++chunk) {
        int k0 = chunk * 256;  // chunks 0..3 read h, 4..5 read x_t
        // Stage A[32][256] hi+lo: 1024 bf16x8 groups per array, 4 per thread.
#pragma unroll
        for (int g = 0; g < 4; ++g) {
            int idx = g * 256 + tid;        // 0..1023
            int r   = idx >> 5;             // batch row 0..31
            int cg  = (idx & 31) * 8;       // col within chunk, step 8
            int k   = k0 + cg;
            const bf16_t *srcH, *srcL;
            if (k < H_) {
                srcH = hInHi + (size_t)r * H_ + k;
                srcL = hInLo + (size_t)r * H_ + k;
            } else {
                size_t off = ((size_t)r * T_ + t) * D_ + (k - H_);
                srcH = XHi + off;
                srcL = XLo + off;
            }
            *(bf16x8*)&aHi[r][cg] = *(const bf16x8*)srcH;
            *(bf16x8*)&aLo[r][cg] = *(const bf16x8*)srcL;
        }
        __syncthreads();
#pragma unroll
        for (int kk = 0; kk < 256; kk += 32) {
            bf16x8 bh  = *(const bf16x8*)(wHiRow + k0 + kk + quad * 8);
            bf16x8 bl  = *(const bf16x8*)(wLoRow + k0 + kk + quad * 8);
            bf16x8 a0h = *(const bf16x8*)&aHi[lcol][kk + quad * 8];
            bf16x8 a0l = *(const bf16x8*)&aLo[lcol][kk + quad * 8];
            bf16x8 a1h = *(const bf16x8*)&aHi[16 + lcol][kk + quad * 8];
            bf16x8 a1l = *(const bf16x8*)&aLo[16 + lcol][kk + quad * 8];
            acc0 = __builtin_amdgcn_mfma_f32_16x16x32_bf16(a0h, bh, acc0, 0, 0, 0);
            acc1 = __builtin_amdgcn_mfma_f32_16x16x32_bf16(a1h, bh, acc1, 0, 0, 0);
            acc0 = __builtin_amdgcn_mfma_f32_16x16x32_bf16(a0l, bh, acc0, 0, 0, 0);
            acc1 = __builtin_amdgcn_mfma_f32_16x16x32_bf16(a1l, bh, acc1, 0, 0, 0);
            acc0 = __builtin_amdgcn_mfma_f32_16x16x32_bf16(a0h, bl, acc0, 0, 0, 0);
            acc1 = __builtin_amdgcn_mfma_f32_16x16x32_bf16(a1h, bl, acc1, 0, 0, 0);
        }
        __syncthreads();
    }

    // Epilogue: z = acc + bias, exchange gates via LDS.
    float bv = bias[nz];
#pragma unroll
    for (int r = 0; r < 4; ++r) {
        zsm[wave][quad * 4 + r][lcol]      = acc0[r] + bv;  // batches 0..15
        zsm[wave][16 + quad * 4 + r][lcol] = acc1[r] + bv;  // batches 16..31
    }
    __syncthreads();

    // Gate math: 32 batches x 16 cols = 512 elements, 2 per thread.
#pragma unroll
    for (int p = tid; p < 512; p += 256) {
        int b  = p >> 4;
        int cc = p & 15;
        float zi = zsm[0][b][cc];
        float zf = zsm[1][b][cc];
        float zg = zsm[2][b][cc];
        float zo = zsm[3][b][cc];
        float ig = 1.f / (1.f + __expf(-zi));
        float fg = 1.f / (1.f + __expf(-zf));
        float og = 1.f / (1.f + __expf(-zo));
        float gg = 1.f - 2.f / (__expf(2.f * zg) + 1.f);   // tanh, inf-safe
        int col = hc0 + cc;
        float cv = c[b * H_ + col];
        float cn = fg * cv + ig * gg;
        c[b * H_ + col] = cn;
        float hn = og * (1.f - 2.f / (__expf(2.f * cn) + 1.f));
        bf16_t hh = (bf16_t)hn;
        hOutHi[b * H_ + col] = hh;
        hOutLo[b * H_ + col] = (bf16_t)(hn - (float)hh);
        if (seqlen[b] - 1 == t) out[b * H_ + col] = hn;
    }
}

// ---------------------------------------------------------------------------
extern "C" void kernel_launch(void* const* d_in, const int* in_sizes, int n_in,
                              void* d_out, int out_size, void* d_ws, size_t ws_size,
                              hipStream_t stream) {
    const float* inputs = (const float*)d_in[0];
    const int*   seqlen = (const int*)d_in[1];
    const float* Wx     = (const float*)d_in[2];
    const float* Wh     = (const float*)d_in[3];
    const float* bias   = (const float*)d_in[4];
    float* out = (float*)d_out;

    char* ws = (char*)d_ws;
    size_t o = 0;
    bf16_t* WtHi = (bf16_t*)(ws + o); o += (size_t)N4H * KTOT * 2;  // 12.6 MB
    bf16_t* WtLo = (bf16_t*)(ws + o); o += (size_t)N4H * KTOT * 2;  // 12.6 MB
    bf16_t* XHi  = (bf16_t*)(ws + o); o += (size_t)B_ * T_ * D_ * 2; // 16.8 MB
    bf16_t* XLo  = (bf16_t*)(ws + o); o += (size_t)B_ * T_ * D_ * 2; // 16.8 MB
    bf16_t* h0Hi = (bf16_t*)(ws + o); o += (size_t)B_ * H_ * 2;
    bf16_t* h0Lo = (bf16_t*)(ws + o); o += (size_t)B_ * H_ * 2;
    float*  cst  = (float*)(ws + o);  o += (size_t)B_ * H_ * 4;
    bf16_t* h1Hi = (bf16_t*)(ws + o); o += (size_t)B_ * H_ * 2;
    bf16_t* h1Lo = (bf16_t*)(ws + o); o += (size_t)B_ * H_ * 2;
    // total ~56.4 MB

    // Weight transpose+split and input split (ws re-poisoned every call, so
    // these run every launch; ~50 us total).
    wconv_kernel<<<dim3(48, 128), dim3(32, 8), 0, stream>>>(Wx, Wh, WtHi, WtLo);
    xconv_kernel<<<(B_ * T_ * D_ / 4) / 256, 256, 0, stream>>>(
        (const float4*)inputs, XHi, XLo);
    // zero h0Hi, h0Lo, c (contiguous in layout)
    hipMemsetAsync(h0Hi, 0, (size_t)B_ * H_ * 2 * 2 + (size_t)B_ * H_ * 4, stream);

    for (int t = 0; t < T_; ++t) {
        const bf16_t *hiH, *hiL;
        bf16_t *hoH, *hoL;
        if ((t & 1) == 0) { hiH = h0Hi; hiL = h0Lo; hoH = h1Hi; hoL = h1Lo; }
        else             { hiH = h1Hi; hiL = h1Lo; hoH = h0Hi; hoL = h0Lo; }
        step_kernel<<<64, 256, 0, stream>>>(WtHi, WtLo, XHi, XLo,
                                            hiH, hiL, hoH, hoL,
                                            cst, bias, seqlen, out, t);
    }
}